// Round 1
// baseline (258.107 us; speedup 1.0000x reference)
//
#include <hip/hip_runtime.h>
#include <stdint.h>

typedef _Float16 half8 __attribute__((ext_vector_type(8)));
typedef float floatx4 __attribute__((ext_vector_type(4)));

// ---------------------------------------------------------------------------
// Kernel 1: normalize x rows (N x 32 f32) -> xhat (N x 32 fp16), unit rows.
// 4 lanes per row, fully coalesced 16B loads/stores.
// ---------------------------------------------------------------------------
__global__ __launch_bounds__(256) void k_norm_x(const float* __restrict__ x,
                                                _Float16* __restrict__ xhat,
                                                int N) {
  int t   = blockIdx.x * 256 + threadIdx.x;
  int row = t >> 2;
  int q   = t & 3;
  if (row >= N) return;
  const float4* xr = reinterpret_cast<const float4*>(x + (size_t)row * 32 + q * 8);
  float4 a = xr[0];
  float4 b = xr[1];
  float ss = a.x * a.x + a.y * a.y + a.z * a.z + a.w * a.w +
             b.x * b.x + b.y * b.y + b.z * b.z + b.w * b.w;
  ss += __shfl_xor(ss, 1);
  ss += __shfl_xor(ss, 2);
  float rn = ss > 0.f ? rsqrtf(ss) : 0.f;
  half8 h;
  h[0] = (_Float16)(a.x * rn); h[1] = (_Float16)(a.y * rn);
  h[2] = (_Float16)(a.z * rn); h[3] = (_Float16)(a.w * rn);
  h[4] = (_Float16)(b.x * rn); h[5] = (_Float16)(b.y * rn);
  h[6] = (_Float16)(b.z * rn); h[7] = (_Float16)(b.w * rn);
  *reinterpret_cast<half8*>(xhat + (size_t)row * 32 + q * 8) = h;
}

// ---------------------------------------------------------------------------
// Kernel 2: pack nei_p (nd,d,3) + nei_e (nd,d,8) -> pe (nd x PEP fp16),
// per-slot layout [p0,p1,p2,0, e0..e7, 0,0,0,0] with each part normalized.
// One thread per (node,slot).
// ---------------------------------------------------------------------------
template <int D, int PEP>
__global__ __launch_bounds__(256) void k_pack_pe(const float* __restrict__ p,
                                                 const float* __restrict__ e,
                                                 _Float16* __restrict__ pe,
                                                 int nd) {
  int idx = blockIdx.x * 256 + threadIdx.x;
  if (idx >= nd * D) return;
  int node = idx / D;
  int slot = idx % D;

  const float* pp = p + (size_t)idx * 3;
  float p0 = pp[0], p1 = pp[1], p2 = pp[2];
  float pn = sqrtf(p0 * p0 + p1 * p1 + p2 * p2);
  float rp = pn > 0.f ? 1.f / pn : 0.f;

  const float4* ee = reinterpret_cast<const float4*>(e + (size_t)idx * 8);
  float4 e0 = ee[0];
  float4 e1 = ee[1];
  float en = sqrtf(e0.x * e0.x + e0.y * e0.y + e0.z * e0.z + e0.w * e0.w +
                   e1.x * e1.x + e1.y * e1.y + e1.z * e1.z + e1.w * e1.w);
  float re = en > 0.f ? 1.f / en : 0.f;

  half8 h0, h1;
  h0[0] = (_Float16)(p0 * rp); h0[1] = (_Float16)(p1 * rp);
  h0[2] = (_Float16)(p2 * rp); h0[3] = (_Float16)0.f;
  h0[4] = (_Float16)(e0.x * re); h0[5] = (_Float16)(e0.y * re);
  h0[6] = (_Float16)(e0.z * re); h0[7] = (_Float16)(e0.w * re);
  h1[0] = (_Float16)(e1.x * re); h1[1] = (_Float16)(e1.y * re);
  h1[2] = (_Float16)(e1.z * re); h1[3] = (_Float16)(e1.w * re);
  h1[4] = (_Float16)0.f; h1[5] = (_Float16)0.f;
  h1[6] = (_Float16)0.f; h1[7] = (_Float16)0.f;

  _Float16* dst = pe + (size_t)node * PEP + slot * 16;
  *reinterpret_cast<half8*>(dst)     = h0;
  *reinterpret_cast<half8*>(dst + 8) = h1;

  half8 z = {};
  if (D == 1) {  // pad [16,32)
    _Float16* pz = pe + (size_t)node * PEP + 16;
    *reinterpret_cast<half8*>(pz)     = z;
    *reinterpret_cast<half8*>(pz + 8) = z;
  }
  if (D == 3 && slot == 0) {  // pad [48,64)
    _Float16* pz = pe + (size_t)node * PEP + 48;
    *reinterpret_cast<half8*>(pz)     = z;
    *reinterpret_cast<half8*>(pz + 8) = z;
  }
}

// ---------------------------------------------------------------------------
// Kernel 3: pack weights -> psi: [k][KDIM] fp16, normalized rows with
// 0.25 (and 1/d) folded in. One block per group (blockIdx = group).
// ---------------------------------------------------------------------------
struct WPtrs { const float *wc, *wn, *wp, *we; };
struct WAll  { WPtrs g[4]; };

__global__ __launch_bounds__(256) void k_pack_w(WAll wa, _Float16* __restrict__ psi) {
  int g = blockIdx.x;      // 0..3
  int d = g + 1;
  int PEP = (d <= 2) ? 32 : 64;
  int KD  = 32 * (1 + d) + PEP;
  _Float16* pg = psi + (size_t)g * (16 * 224);

  for (int i = threadIdx.x; i < 16 * KD; i += 256) pg[i] = (_Float16)0.f;
  __syncthreads();

  int k     = threadIdx.x & 15;
  int piece = threadIdx.x >> 4;
  int np    = 1 + 3 * d;
  if (piece >= np) return;

  const WPtrs& w = wa.g[g];
  const float* src;
  _Float16* dst;
  int len;
  float scale;
  if (piece == 0) {
    src = w.wc + k * 32; dst = pg + k * KD; len = 32; scale = 0.25f;
  } else if (piece <= d) {
    int s = piece - 1;
    src = w.wn + (size_t)(k * d + s) * 32; dst = pg + k * KD + 32 * (1 + s);
    len = 32; scale = 0.25f / d;
  } else if (piece <= 2 * d) {
    int s = piece - 1 - d;
    src = w.wp + (size_t)(k * d + s) * 3;
    dst = pg + k * KD + 32 * (1 + d) + 16 * s;
    len = 3; scale = 0.25f / d;
  } else {
    int s = piece - 1 - 2 * d;
    src = w.we + (size_t)(k * d + s) * 8;
    dst = pg + k * KD + 32 * (1 + d) + 16 * s + 4;
    len = 8; scale = 0.25f / d;
  }
  float ss = 0.f;
  for (int j = 0; j < len; ++j) ss += src[j] * src[j];
  float n  = sqrtf(ss);
  float sc = n > 0.f ? scale / n : 0.f;
  for (int j = 0; j < len; ++j) dst[j] = (_Float16)(src[j] * sc);
}

// ---------------------------------------------------------------------------
// Kernel 4 (main, per group): gathered MFMA GEMM.
// Each wave handles 16 nodes: A frags gathered from xhat/pe, B frags (weights)
// in registers, one fp32 accumulator, writes full 64-float output rows
// (score in columns [(D-1)*16, D*16), zeros elsewhere).
// MFMA 16x16x32 f16:  A row = lane&15, B col = lane&15, k-chunk = lane>>4.
// C/D: col = lane&15, row = (lane>>4)*4 + reg  [verified layout].
// ---------------------------------------------------------------------------
template <int D, int PEP>
__global__ __launch_bounds__(256) void k_main(const _Float16* __restrict__ xhat,
                                              const _Float16* __restrict__ pe,
                                              const _Float16* __restrict__ psi,
                                              const int* __restrict__ sel,
                                              const int* __restrict__ nei,
                                              float* __restrict__ out,
                                              int nd) {
  constexpr int NMF  = 1 + D;
  constexpr int PEMF = PEP / 32;
  constexpr int NF   = NMF + PEMF;
  constexpr int KD   = 32 * NF;

  int wave    = threadIdx.x >> 6;
  int lane    = threadIdx.x & 63;
  int nchunks = (nd + 15) >> 4;
  int chunk   = blockIdx.x * 4 + wave;
  if (chunk >= nchunks) return;
  int i0 = chunk << 4;
  int r  = lane & 15;   // A row / B col / C col
  int c  = lane >> 4;   // k-chunk

  // B fragments: loaded once, constant for the whole kernel.
  half8 bx[NF];
  {
    const _Float16* pb = psi + (size_t)r * KD + c * 8;
#pragma unroll
    for (int t = 0; t < NF; ++t)
      bx[t] = *reinterpret_cast<const half8*>(pb + 32 * t);
  }

  int ri = i0 + r;
  if (ri > nd - 1) ri = nd - 1;
  int sidx = sel[ri];

  floatx4 acc = {0.f, 0.f, 0.f, 0.f};
  {
    half8 a = *reinterpret_cast<const half8*>(xhat + (size_t)sidx * 32 + c * 8);
    acc = __builtin_amdgcn_mfma_f32_16x16x32_f16(a, bx[0], acc, 0, 0, 0);
  }
#pragma unroll
  for (int s = 0; s < D; ++s) {
    int gi = nei[(size_t)ri * D + s];
    half8 a = *reinterpret_cast<const half8*>(xhat + (size_t)gi * 32 + c * 8);
    acc = __builtin_amdgcn_mfma_f32_16x16x32_f16(a, bx[1 + s], acc, 0, 0, 0);
  }
#pragma unroll
  for (int m = 0; m < PEMF; ++m) {
    half8 a = *reinterpret_cast<const half8*>(pe + (size_t)ri * PEP + 32 * m + c * 8);
    acc = __builtin_amdgcn_mfma_f32_16x16x32_f16(a, bx[NMF + m], acc, 0, 0, 0);
  }

  // Writeback: lane covers C rows (c*4+j), col r. Full 64-col row per node.
#pragma unroll
  for (int j = 0; j < 4; ++j) {
    int n  = i0 + c * 4 + j;
    int so = __shfl(sidx, c * 4 + j);  // sel[i0 + c*4 + j]
    if (n < nd) {
      float* orow = out + (size_t)so * 64 + r;
#pragma unroll
      for (int q = 0; q < 4; ++q)
        orow[q * 16] = (q == D - 1) ? acc[j] : 0.f;
    }
  }
}

// ---------------------------------------------------------------------------
extern "C" void kernel_launch(void* const* d_in, const int* in_sizes, int n_in,
                              void* d_out, int out_size, void* d_ws, size_t ws_size,
                              hipStream_t stream) {
  const float* x = (const float*)d_in[0];
  int N = in_sizes[0] / 32;

  const int*   sel[4];
  const int*   nei[4];
  const float* nep[4];
  const float* nee[4];
  WAll wa;
  int nd[4];
  for (int g = 0; g < 4; ++g) {
    int b = 1 + g * 8;
    sel[g]     = (const int*)d_in[b + 0];
    nei[g]     = (const int*)d_in[b + 1];
    nep[g]     = (const float*)d_in[b + 2];
    nee[g]     = (const float*)d_in[b + 3];
    wa.g[g].wc = (const float*)d_in[b + 4];
    wa.g[g].wn = (const float*)d_in[b + 5];
    wa.g[g].wp = (const float*)d_in[b + 6];
    wa.g[g].we = (const float*)d_in[b + 7];
    nd[g]      = in_sizes[b];
  }
  float* out = (float*)d_out;

  // workspace layout
  char* ws = (char*)d_ws;
  auto align256 = [](size_t o) { return (o + 255) & ~(size_t)255; };
  _Float16* xhat = (_Float16*)ws;
  size_t off = (size_t)N * 32 * 2;
  const int PEP[4] = {32, 32, 64, 64};
  _Float16* pe[4];
  for (int g = 0; g < 4; ++g) {
    off = align256(off);
    pe[g] = (_Float16*)(ws + off);
    off += (size_t)nd[g] * PEP[g] * 2;
  }
  off = align256(off);
  _Float16* psi = (_Float16*)(ws + off);

  // 1) normalize x
  k_norm_x<<<(N + 63) / 64, 256, 0, stream>>>(x, xhat, N);

  // 2) pack p/e per group
  k_pack_pe<1, 32><<<(nd[0] * 1 + 255) / 256, 256, 0, stream>>>(nep[0], nee[0], pe[0], nd[0]);
  k_pack_pe<2, 32><<<(nd[1] * 2 + 255) / 256, 256, 0, stream>>>(nep[1], nee[1], pe[1], nd[1]);
  k_pack_pe<3, 64><<<(nd[2] * 3 + 255) / 256, 256, 0, stream>>>(nep[2], nee[2], pe[2], nd[2]);
  k_pack_pe<4, 64><<<(nd[3] * 4 + 255) / 256, 256, 0, stream>>>(nep[3], nee[3], pe[3], nd[3]);

  // 3) pack weights (4 blocks, one per group)
  k_pack_w<<<4, 256, 0, stream>>>(wa, psi);

  // 4) main gathered-MFMA kernels
  auto blocksFor = [](int n) { int ch = (n + 15) / 16; return (ch + 3) / 4; };
  k_main<1, 32><<<blocksFor(nd[0]), 256, 0, stream>>>(xhat, pe[0], psi + 0 * 16 * 224, sel[0], nei[0], out, nd[0]);
  k_main<2, 32><<<blocksFor(nd[1]), 256, 0, stream>>>(xhat, pe[1], psi + 1 * 16 * 224, sel[1], nei[1], out, nd[1]);
  k_main<3, 64><<<blocksFor(nd[2]), 256, 0, stream>>>(xhat, pe[2], psi + 2 * 16 * 224, sel[2], nei[2], out, nd[2]);
  k_main<4, 64><<<blocksFor(nd[3]), 256, 0, stream>>>(xhat, pe[3], psi + 3 * 16 * 224, sel[3], nei[3], out, nd[3]);
}

// Round 2
// 230.307 us; speedup vs baseline: 1.1207x; 1.1207x over previous
//
#include <hip/hip_runtime.h>
#include <stdint.h>

typedef _Float16 half8 __attribute__((ext_vector_type(8)));
typedef float floatx4 __attribute__((ext_vector_type(4)));

struct WPtrs { const float *wc, *wn, *wp, *we; };

// ---------------------------------------------------------------------------
// pack one (node,slot) of nei_p/nei_e into the fp16 pe row
// layout per slot: [p0,p1,p2,0, e0..e7, 0,0,0,0], each part L2-normalized
// ---------------------------------------------------------------------------
template <int D, int PEP>
__device__ inline void pack_pe_one(const float* __restrict__ p,
                                   const float* __restrict__ e,
                                   _Float16* __restrict__ pe, int idx) {
  int node = idx / D;
  int slot = idx % D;

  const float* pp = p + (size_t)idx * 3;
  float p0 = pp[0], p1 = pp[1], p2 = pp[2];
  float pn = sqrtf(p0 * p0 + p1 * p1 + p2 * p2);
  float rp = pn > 0.f ? 1.f / pn : 0.f;

  const float4* ee = reinterpret_cast<const float4*>(e + (size_t)idx * 8);
  float4 e0 = ee[0];
  float4 e1 = ee[1];
  float en = sqrtf(e0.x * e0.x + e0.y * e0.y + e0.z * e0.z + e0.w * e0.w +
                   e1.x * e1.x + e1.y * e1.y + e1.z * e1.z + e1.w * e1.w);
  float re = en > 0.f ? 1.f / en : 0.f;

  half8 h0, h1;
  h0[0] = (_Float16)(p0 * rp); h0[1] = (_Float16)(p1 * rp);
  h0[2] = (_Float16)(p2 * rp); h0[3] = (_Float16)0.f;
  h0[4] = (_Float16)(e0.x * re); h0[5] = (_Float16)(e0.y * re);
  h0[6] = (_Float16)(e0.z * re); h0[7] = (_Float16)(e0.w * re);
  h1[0] = (_Float16)(e1.x * re); h1[1] = (_Float16)(e1.y * re);
  h1[2] = (_Float16)(e1.z * re); h1[3] = (_Float16)(e1.w * re);
  h1[4] = (_Float16)0.f; h1[5] = (_Float16)0.f;
  h1[6] = (_Float16)0.f; h1[7] = (_Float16)0.f;

  _Float16* dst = pe + (size_t)node * PEP + slot * 16;
  *reinterpret_cast<half8*>(dst)     = h0;
  *reinterpret_cast<half8*>(dst + 8) = h1;

  half8 z = {};
  if (D == 1) {  // pad [16,32)
    _Float16* pz = pe + (size_t)node * PEP + 16;
    *reinterpret_cast<half8*>(pz)     = z;
    *reinterpret_cast<half8*>(pz + 8) = z;
  }
  if (D == 3 && slot == 0) {  // pad [48,64)
    _Float16* pz = pe + (size_t)node * PEP + 48;
    *reinterpret_cast<half8*>(pz)     = z;
    *reinterpret_cast<half8*>(pz + 8) = z;
  }
}

// ---------------------------------------------------------------------------
// Fused prep kernel: grid = [norm blocks | pe blocks | 4 weight blocks]
// All three parts are mutually independent.
// ---------------------------------------------------------------------------
struct PrepArgs {
  const float* x; _Float16* xhat; int N; int nb_norm;
  const float* p[4]; const float* e[4]; _Float16* pe[4];
  int slotOff[5]; int nb_pe;
  WPtrs w[4]; _Float16* psi;
};

__global__ __launch_bounds__(256) void k_prep(PrepArgs a) {
  int bid = blockIdx.x, tid = threadIdx.x;

  if (bid < a.nb_norm) {
    // ---- normalize x rows: 4 lanes per row ----
    int row = bid * 64 + (tid >> 2);
    int q   = tid & 3;
    if (row >= a.N) return;
    const float4* xr = reinterpret_cast<const float4*>(a.x + (size_t)row * 32 + q * 8);
    float4 va = xr[0];
    float4 vb = xr[1];
    float ss = va.x * va.x + va.y * va.y + va.z * va.z + va.w * va.w +
               vb.x * vb.x + vb.y * vb.y + vb.z * vb.z + vb.w * vb.w;
    ss += __shfl_xor(ss, 1);
    ss += __shfl_xor(ss, 2);
    float rn = ss > 0.f ? rsqrtf(ss) : 0.f;
    half8 h;
    h[0] = (_Float16)(va.x * rn); h[1] = (_Float16)(va.y * rn);
    h[2] = (_Float16)(va.z * rn); h[3] = (_Float16)(va.w * rn);
    h[4] = (_Float16)(vb.x * rn); h[5] = (_Float16)(vb.y * rn);
    h[6] = (_Float16)(vb.z * rn); h[7] = (_Float16)(vb.w * rn);
    *reinterpret_cast<half8*>(a.xhat + (size_t)row * 32 + q * 8) = h;
    return;
  }

  if (bid < a.nb_norm + a.nb_pe) {
    // ---- pack p/e slots, all groups ----
    int s = (bid - a.nb_norm) * 256 + tid;
    if (s >= a.slotOff[4]) return;
    if      (s < a.slotOff[1]) pack_pe_one<1, 32>(a.p[0], a.e[0], a.pe[0], s);
    else if (s < a.slotOff[2]) pack_pe_one<2, 32>(a.p[1], a.e[1], a.pe[1], s - a.slotOff[1]);
    else if (s < a.slotOff[3]) pack_pe_one<3, 64>(a.p[2], a.e[2], a.pe[2], s - a.slotOff[2]);
    else                       pack_pe_one<4, 64>(a.p[3], a.e[3], a.pe[3], s - a.slotOff[3]);
    return;
  }

  // ---- pack weights: one block per group ----
  int g = bid - a.nb_norm - a.nb_pe;  // 0..3
  int d = g + 1;
  int PEP = (d <= 2) ? 32 : 64;
  int KD  = 32 * (1 + d) + PEP;
  _Float16* pg = a.psi + (size_t)g * (16 * 224);

  for (int i = tid; i < 16 * KD; i += 256) pg[i] = (_Float16)0.f;
  __syncthreads();

  int k     = tid & 15;
  int piece = tid >> 4;
  int np    = 1 + 3 * d;
  if (piece >= np) return;

  const WPtrs& w = a.w[g];
  const float* src;
  _Float16* dst;
  int len;
  float scale;
  if (piece == 0) {
    src = w.wc + k * 32; dst = pg + k * KD; len = 32; scale = 0.25f;
  } else if (piece <= d) {
    int s = piece - 1;
    src = w.wn + (size_t)(k * d + s) * 32; dst = pg + k * KD + 32 * (1 + s);
    len = 32; scale = 0.25f / d;
  } else if (piece <= 2 * d) {
    int s = piece - 1 - d;
    src = w.wp + (size_t)(k * d + s) * 3;
    dst = pg + k * KD + 32 * (1 + d) + 16 * s;
    len = 3; scale = 0.25f / d;
  } else {
    int s = piece - 1 - 2 * d;
    src = w.we + (size_t)(k * d + s) * 8;
    dst = pg + k * KD + 32 * (1 + d) + 16 * s + 4;
    len = 8; scale = 0.25f / d;
  }
  float ss = 0.f;
  for (int j = 0; j < len; ++j) ss += src[j] * src[j];
  float n  = sqrtf(ss);
  float sc = n > 0.f ? scale / n : 0.f;
  for (int j = 0; j < len; ++j) dst[j] = (_Float16)(src[j] * sc);
}

// ---------------------------------------------------------------------------
// Fused main kernel: gathered MFMA GEMM for all 4 groups in one launch.
// MFMA 16x16x32 f16:  A row = lane&15, B col = lane&15, k-chunk = lane>>4.
// C/D: col = lane&15, row = (lane>>4)*4 + reg  [verified layout].
// ---------------------------------------------------------------------------
struct MainArgs {
  const _Float16* xhat;
  const _Float16* pe[4];
  const _Float16* psi;       // group g at psi + g*16*224, row stride KD(g)
  const int* sel[4];
  const int* nei[4];
  float* out;
  int nd[4];
  int blkOff[5];             // cumulative block offsets per group
};

template <int D, int PEP>
__device__ inline void main_one(const MainArgs& a, int g, int blk) {
  constexpr int NMF  = 1 + D;
  constexpr int PEMF = PEP / 32;
  constexpr int NF   = NMF + PEMF;
  constexpr int KD   = 32 * NF;

  const _Float16* xhat = a.xhat;
  const _Float16* pe   = a.pe[g];
  const _Float16* psi  = a.psi + (size_t)g * (16 * 224);
  const int* sel = a.sel[g];
  const int* nei = a.nei[g];
  int nd = a.nd[g];

  int wave    = threadIdx.x >> 6;
  int lane    = threadIdx.x & 63;
  int nchunks = (nd + 15) >> 4;
  int chunk   = blk * 4 + wave;
  if (chunk >= nchunks) return;
  int i0 = chunk << 4;
  int r  = lane & 15;   // A row / B col / C col
  int c  = lane >> 4;   // k-chunk

  half8 bx[NF];
  {
    const _Float16* pb = psi + (size_t)r * KD + c * 8;
#pragma unroll
    for (int t = 0; t < NF; ++t)
      bx[t] = *reinterpret_cast<const half8*>(pb + 32 * t);
  }

  int ri = i0 + r;
  if (ri > nd - 1) ri = nd - 1;
  int sidx = sel[ri];

  floatx4 acc = {0.f, 0.f, 0.f, 0.f};
  {
    half8 av = *reinterpret_cast<const half8*>(xhat + (size_t)sidx * 32 + c * 8);
    acc = __builtin_amdgcn_mfma_f32_16x16x32_f16(av, bx[0], acc, 0, 0, 0);
  }
#pragma unroll
  for (int s = 0; s < D; ++s) {
    int gi = nei[(size_t)ri * D + s];
    half8 av = *reinterpret_cast<const half8*>(xhat + (size_t)gi * 32 + c * 8);
    acc = __builtin_amdgcn_mfma_f32_16x16x32_f16(av, bx[1 + s], acc, 0, 0, 0);
  }
#pragma unroll
  for (int m = 0; m < PEMF; ++m) {
    half8 av = *reinterpret_cast<const half8*>(pe + (size_t)ri * PEP + 32 * m + c * 8);
    acc = __builtin_amdgcn_mfma_f32_16x16x32_f16(av, bx[NMF + m], acc, 0, 0, 0);
  }

  // Writeback: lane covers C rows (c*4+j), col r. Full 64-col row per node.
#pragma unroll
  for (int j = 0; j < 4; ++j) {
    int n  = i0 + c * 4 + j;
    int so = __shfl(sidx, c * 4 + j);  // sel[i0 + c*4 + j]
    if (n < nd) {
      float* orow = a.out + (size_t)so * 64 + r;
#pragma unroll
      for (int q = 0; q < 4; ++q)
        orow[q * 16] = (q == D - 1) ? acc[j] : 0.f;
    }
  }
}

__global__ __launch_bounds__(256) void k_main(MainArgs a) {
  int bid = blockIdx.x;
  if (bid < a.blkOff[1])      main_one<1, 32>(a, 0, bid);
  else if (bid < a.blkOff[2]) main_one<2, 32>(a, 1, bid - a.blkOff[1]);
  else if (bid < a.blkOff[3]) main_one<3, 64>(a, 2, bid - a.blkOff[2]);
  else                        main_one<4, 64>(a, 3, bid - a.blkOff[3]);
}

// ---------------------------------------------------------------------------
extern "C" void kernel_launch(void* const* d_in, const int* in_sizes, int n_in,
                              void* d_out, int out_size, void* d_ws, size_t ws_size,
                              hipStream_t stream) {
  const float* x = (const float*)d_in[0];
  int N = in_sizes[0] / 32;

  PrepArgs pa;
  MainArgs ma;
  pa.x = x; pa.N = N;
  int nd[4];
  for (int g = 0; g < 4; ++g) {
    int b = 1 + g * 8;
    ma.sel[g]  = (const int*)d_in[b + 0];
    ma.nei[g]  = (const int*)d_in[b + 1];
    pa.p[g]    = (const float*)d_in[b + 2];
    pa.e[g]    = (const float*)d_in[b + 3];
    pa.w[g].wc = (const float*)d_in[b + 4];
    pa.w[g].wn = (const float*)d_in[b + 5];
    pa.w[g].wp = (const float*)d_in[b + 6];
    pa.w[g].we = (const float*)d_in[b + 7];
    nd[g] = in_sizes[b];
    ma.nd[g] = nd[g];
  }
  ma.out = (float*)d_out;

  // workspace layout
  char* ws = (char*)d_ws;
  auto align256 = [](size_t o) { return (o + 255) & ~(size_t)255; };
  _Float16* xhat = (_Float16*)ws;
  size_t off = (size_t)N * 32 * 2;
  const int PEP[4] = {32, 32, 64, 64};
  for (int g = 0; g < 4; ++g) {
    off = align256(off);
    pa.pe[g] = (_Float16*)(ws + off);
    ma.pe[g] = pa.pe[g];
    off += (size_t)nd[g] * PEP[g] * 2;
  }
  off = align256(off);
  _Float16* psi = (_Float16*)(ws + off);
  pa.psi = psi;
  ma.psi = psi;
  pa.xhat = xhat;
  ma.xhat = xhat;

  // prep grid: [norm | pe | 4 weight blocks]
  pa.nb_norm = (N + 63) / 64;
  pa.slotOff[0] = 0;
  for (int g = 0; g < 4; ++g) pa.slotOff[g + 1] = pa.slotOff[g] + nd[g] * (g + 1);
  pa.nb_pe = (pa.slotOff[4] + 255) / 256;
  int prep_blocks = pa.nb_norm + pa.nb_pe + 4;

  // main grid: cumulative per-group block offsets (4 waves/block, 16 nodes/wave)
  ma.blkOff[0] = 0;
  for (int g = 0; g < 4; ++g) {
    int ch = (nd[g] + 15) / 16;
    ma.blkOff[g + 1] = ma.blkOff[g] + (ch + 3) / 4;
  }

  k_prep<<<prep_blocks, 256, 0, stream>>>(pa);
  k_main<<<ma.blkOff[4], 256, 0, stream>>>(ma);
}

// Round 3
// 230.084 us; speedup vs baseline: 1.1218x; 1.0010x over previous
//
#include <hip/hip_runtime.h>
#include <stdint.h>

typedef _Float16 half8 __attribute__((ext_vector_type(8)));
typedef float floatx4 __attribute__((ext_vector_type(4)));

struct WPtrs { const float *wc, *wn, *wp, *we; };

// ---------------------------------------------------------------------------
// pack one (node,slot) of nei_p/nei_e into the fp16 pe row
// layout per slot: [p0,p1,p2,0, e0..e7, 0,0,0,0], each part L2-normalized
// ---------------------------------------------------------------------------
template <int D, int PEP>
__device__ inline void pack_pe_one(const float* __restrict__ p,
                                   const float* __restrict__ e,
                                   _Float16* __restrict__ pe, int idx) {
  int node = idx / D;
  int slot = idx % D;

  const float* pp = p + (size_t)idx * 3;
  float p0 = pp[0], p1 = pp[1], p2 = pp[2];
  float pn = sqrtf(p0 * p0 + p1 * p1 + p2 * p2);
  float rp = pn > 0.f ? 1.f / pn : 0.f;

  const float4* ee = reinterpret_cast<const float4*>(e + (size_t)idx * 8);
  float4 e0 = ee[0];
  float4 e1 = ee[1];
  float en = sqrtf(e0.x * e0.x + e0.y * e0.y + e0.z * e0.z + e0.w * e0.w +
                   e1.x * e1.x + e1.y * e1.y + e1.z * e1.z + e1.w * e1.w);
  float re = en > 0.f ? 1.f / en : 0.f;

  half8 h0, h1;
  h0[0] = (_Float16)(p0 * rp); h0[1] = (_Float16)(p1 * rp);
  h0[2] = (_Float16)(p2 * rp); h0[3] = (_Float16)0.f;
  h0[4] = (_Float16)(e0.x * re); h0[5] = (_Float16)(e0.y * re);
  h0[6] = (_Float16)(e0.z * re); h0[7] = (_Float16)(e0.w * re);
  h1[0] = (_Float16)(e1.x * re); h1[1] = (_Float16)(e1.y * re);
  h1[2] = (_Float16)(e1.z * re); h1[3] = (_Float16)(e1.w * re);
  h1[4] = (_Float16)0.f; h1[5] = (_Float16)0.f;
  h1[6] = (_Float16)0.f; h1[7] = (_Float16)0.f;

  _Float16* dst = pe + (size_t)node * PEP + slot * 16;
  *reinterpret_cast<half8*>(dst)     = h0;
  *reinterpret_cast<half8*>(dst + 8) = h1;

  half8 z = {};
  if (D == 1) {  // pad [16,32)
    _Float16* pz = pe + (size_t)node * PEP + 16;
    *reinterpret_cast<half8*>(pz)     = z;
    *reinterpret_cast<half8*>(pz + 8) = z;
  }
  if (D == 3 && slot == 0) {  // pad [48,64)
    _Float16* pz = pe + (size_t)node * PEP + 48;
    *reinterpret_cast<half8*>(pz)     = z;
    *reinterpret_cast<half8*>(pz + 8) = z;
  }
}

// ---------------------------------------------------------------------------
// Fused prep kernel: grid = [norm blocks | pe blocks | 4 weight blocks]
// All three parts are mutually independent.
// ---------------------------------------------------------------------------
struct PrepArgs {
  const float* x; _Float16* xhat; int N; int nb_norm;
  const float* p[4]; const float* e[4]; _Float16* pe[4];
  int slotOff[5]; int nb_pe;
  WPtrs w[4]; _Float16* psi;
};

__global__ __launch_bounds__(256) void k_prep(PrepArgs a) {
  int bid = blockIdx.x, tid = threadIdx.x;

  if (bid < a.nb_norm) {
    // ---- normalize x rows: 4 lanes per row ----
    int row = bid * 64 + (tid >> 2);
    int q   = tid & 3;
    if (row >= a.N) return;
    const float4* xr = reinterpret_cast<const float4*>(a.x + (size_t)row * 32 + q * 8);
    float4 va = xr[0];
    float4 vb = xr[1];
    float ss = va.x * va.x + va.y * va.y + va.z * va.z + va.w * va.w +
               vb.x * vb.x + vb.y * vb.y + vb.z * vb.z + vb.w * vb.w;
    ss += __shfl_xor(ss, 1);
    ss += __shfl_xor(ss, 2);
    float rn = ss > 0.f ? rsqrtf(ss) : 0.f;
    half8 h;
    h[0] = (_Float16)(va.x * rn); h[1] = (_Float16)(va.y * rn);
    h[2] = (_Float16)(va.z * rn); h[3] = (_Float16)(va.w * rn);
    h[4] = (_Float16)(vb.x * rn); h[5] = (_Float16)(vb.y * rn);
    h[6] = (_Float16)(vb.z * rn); h[7] = (_Float16)(vb.w * rn);
    *reinterpret_cast<half8*>(a.xhat + (size_t)row * 32 + q * 8) = h;
    return;
  }

  if (bid < a.nb_norm + a.nb_pe) {
    // ---- pack p/e slots, all groups ----
    int s = (bid - a.nb_norm) * 256 + tid;
    if (s >= a.slotOff[4]) return;
    if      (s < a.slotOff[1]) pack_pe_one<1, 32>(a.p[0], a.e[0], a.pe[0], s);
    else if (s < a.slotOff[2]) pack_pe_one<2, 32>(a.p[1], a.e[1], a.pe[1], s - a.slotOff[1]);
    else if (s < a.slotOff[3]) pack_pe_one<3, 64>(a.p[2], a.e[2], a.pe[2], s - a.slotOff[2]);
    else                       pack_pe_one<4, 64>(a.p[3], a.e[3], a.pe[3], s - a.slotOff[3]);
    return;
  }

  // ---- pack weights: one block per group ----
  int g = bid - a.nb_norm - a.nb_pe;  // 0..3
  int d = g + 1;
  int PEP = (d <= 2) ? 32 : 64;
  int KD  = 32 * (1 + d) + PEP;
  _Float16* pg = a.psi + (size_t)g * (16 * 224);

  for (int i = tid; i < 16 * KD; i += 256) pg[i] = (_Float16)0.f;
  __syncthreads();

  int k     = tid & 15;
  int piece = tid >> 4;
  int np    = 1 + 3 * d;
  if (piece >= np) return;

  const WPtrs& w = a.w[g];
  const float* src;
  _Float16* dst;
  int len;
  float scale;
  if (piece == 0) {
    src = w.wc + k * 32; dst = pg + k * KD; len = 32; scale = 0.25f;
  } else if (piece <= d) {
    int s = piece - 1;
    src = w.wn + (size_t)(k * d + s) * 32; dst = pg + k * KD + 32 * (1 + s);
    len = 32; scale = 0.25f / d;
  } else if (piece <= 2 * d) {
    int s = piece - 1 - d;
    src = w.wp + (size_t)(k * d + s) * 3;
    dst = pg + k * KD + 32 * (1 + d) + 16 * s;
    len = 3; scale = 0.25f / d;
  } else {
    int s = piece - 1 - 2 * d;
    src = w.we + (size_t)(k * d + s) * 8;
    dst = pg + k * KD + 32 * (1 + d) + 16 * s + 4;
    len = 8; scale = 0.25f / d;
  }
  float ss = 0.f;
  for (int j = 0; j < len; ++j) ss += src[j] * src[j];
  float n  = sqrtf(ss);
  float sc = n > 0.f ? scale / n : 0.f;
  for (int j = 0; j < len; ++j) dst[j] = (_Float16)(src[j] * sc);
}

// ---------------------------------------------------------------------------
// Fused main kernel: gathered MFMA GEMM for all 4 groups in one launch.
// MFMA 16x16x32 f16:  A row = lane&15, B col = lane&15, k-chunk = lane>>4.
// C/D: col = lane&15, row = (lane>>4)*4 + reg  [verified layout].
// ---------------------------------------------------------------------------
struct MainArgs {
  const _Float16* xhat;
  const _Float16* pe[4];
  const _Float16* psi;       // group g at psi + g*16*224, row stride KD(g)
  const int* sel[4];
  const int* nei[4];
  float* out;
  int nd[4];
  int blkOff[5];             // cumulative block offsets per group
};

template <int D, int PEP>
__device__ inline void main_one(const MainArgs& a, int g, int blk) {
  constexpr int NMF  = 1 + D;
  constexpr int PEMF = PEP / 32;
  constexpr int NF   = NMF + PEMF;
  constexpr int KD   = 32 * NF;

  const _Float16* xhat = a.xhat;
  const _Float16* pe   = a.pe[g];
  const _Float16* psi  = a.psi + (size_t)g * (16 * 224);
  const int* sel = a.sel[g];
  const int* nei = a.nei[g];
  int nd = a.nd[g];

  int wave    = threadIdx.x >> 6;
  int lane    = threadIdx.x & 63;
  int nchunks = (nd + 15) >> 4;
  int chunk   = blk * 4 + wave;
  if (chunk >= nchunks) return;
  int i0 = chunk << 4;
  int r  = lane & 15;   // A row / B col / C col
  int c  = lane >> 4;   // k-chunk

  half8 bx[NF];
  {
    const _Float16* pb = psi + (size_t)r * KD + c * 8;
#pragma unroll
    for (int t = 0; t < NF; ++t)
      bx[t] = *reinterpret_cast<const half8*>(pb + 32 * t);
  }

  int ri = i0 + r;
  if (ri > nd - 1) ri = nd - 1;
  int sidx = sel[ri];

  floatx4 acc = {0.f, 0.f, 0.f, 0.f};
  {
    half8 av = *reinterpret_cast<const half8*>(xhat + (size_t)sidx * 32 + c * 8);
    acc = __builtin_amdgcn_mfma_f32_16x16x32_f16(av, bx[0], acc, 0, 0, 0);
  }
#pragma unroll
  for (int s = 0; s < D; ++s) {
    int gi = nei[(size_t)ri * D + s];
    half8 av = *reinterpret_cast<const half8*>(xhat + (size_t)gi * 32 + c * 8);
    acc = __builtin_amdgcn_mfma_f32_16x16x32_f16(av, bx[1 + s], acc, 0, 0, 0);
  }
#pragma unroll
  for (int m = 0; m < PEMF; ++m) {
    half8 av = *reinterpret_cast<const half8*>(pe + (size_t)ri * PEP + 32 * m + c * 8);
    acc = __builtin_amdgcn_mfma_f32_16x16x32_f16(av, bx[NMF + m], acc, 0, 0, 0);
  }

  // Writeback: lane covers C rows (c*4+j), col r. Full 64-col row per node.
#pragma unroll
  for (int j = 0; j < 4; ++j) {
    int n  = i0 + c * 4 + j;
    int so = __shfl(sidx, c * 4 + j);  // sel[i0 + c*4 + j]
    if (n < nd) {
      float* orow = a.out + (size_t)so * 64 + r;
#pragma unroll
      for (int q = 0; q < 4; ++q)
        orow[q * 16] = (q == D - 1) ? acc[j] : 0.f;
    }
  }
}

__global__ __launch_bounds__(256) void k_main(MainArgs a) {
  int bid = blockIdx.x;
  if (bid < a.blkOff[1])      main_one<1, 32>(a, 0, bid);
  else if (bid < a.blkOff[2]) main_one<2, 32>(a, 1, bid - a.blkOff[1]);
  else if (bid < a.blkOff[3]) main_one<3, 64>(a, 2, bid - a.blkOff[2]);
  else                        main_one<4, 64>(a, 3, bid - a.blkOff[3]);
}

// ---------------------------------------------------------------------------
extern "C" void kernel_launch(void* const* d_in, const int* in_sizes, int n_in,
                              void* d_out, int out_size, void* d_ws, size_t ws_size,
                              hipStream_t stream) {
  const float* x = (const float*)d_in[0];
  int N = in_sizes[0] / 32;

  PrepArgs pa;
  MainArgs ma;
  pa.x = x; pa.N = N;
  int nd[4];
  for (int g = 0; g < 4; ++g) {
    int b = 1 + g * 8;
    ma.sel[g]  = (const int*)d_in[b + 0];
    ma.nei[g]  = (const int*)d_in[b + 1];
    pa.p[g]    = (const float*)d_in[b + 2];
    pa.e[g]    = (const float*)d_in[b + 3];
    pa.w[g].wc = (const float*)d_in[b + 4];
    pa.w[g].wn = (const float*)d_in[b + 5];
    pa.w[g].wp = (const float*)d_in[b + 6];
    pa.w[g].we = (const float*)d_in[b + 7];
    nd[g] = in_sizes[b];
    ma.nd[g] = nd[g];
  }
  ma.out = (float*)d_out;

  // workspace layout
  char* ws = (char*)d_ws;
  auto align256 = [](size_t o) { return (o + 255) & ~(size_t)255; };
  _Float16* xhat = (_Float16*)ws;
  size_t off = (size_t)N * 32 * 2;
  const int PEP[4] = {32, 32, 64, 64};
  for (int g = 0; g < 4; ++g) {
    off = align256(off);
    pa.pe[g] = (_Float16*)(ws + off);
    ma.pe[g] = pa.pe[g];
    off += (size_t)nd[g] * PEP[g] * 2;
  }
  off = align256(off);
  _Float16* psi = (_Float16*)(ws + off);
  pa.psi = psi;
  ma.psi = psi;
  pa.xhat = xhat;
  ma.xhat = xhat;

  // prep grid: [norm | pe | 4 weight blocks]
  pa.nb_norm = (N + 63) / 64;
  pa.slotOff[0] = 0;
  for (int g = 0; g < 4; ++g) pa.slotOff[g + 1] = pa.slotOff[g] + nd[g] * (g + 1);
  pa.nb_pe = (pa.slotOff[4] + 255) / 256;
  int prep_blocks = pa.nb_norm + pa.nb_pe + 4;

  // main grid: cumulative per-group block offsets (4 waves/block, 16 nodes/wave)
  ma.blkOff[0] = 0;
  for (int g = 0; g < 4; ++g) {
    int ch = (nd[g] + 15) / 16;
    ma.blkOff[g + 1] = ma.blkOff[g] + (ch + 3) / 4;
  }

  k_prep<<<prep_blocks, 256, 0, stream>>>(pa);
  k_main<<<ma.blkOff[4], 256, 0, stream>>>(ma);
}

// Round 4
// 215.326 us; speedup vs baseline: 1.1987x; 1.0685x over previous
//
#include <hip/hip_runtime.h>
#include <stdint.h>

typedef _Float16 half8 __attribute__((ext_vector_type(8)));
typedef float floatx4 __attribute__((ext_vector_type(4)));

struct WPtrs { const float *wc, *wn, *wp, *we; };

// ---------------------------------------------------------------------------
// pack one (node,slot) of nei_p/nei_e into the fp16 pe row
// layout per slot: [p0,p1,p2,0, e0..e7, 0,0,0,0], each part L2-normalized
// ---------------------------------------------------------------------------
template <int D, int PEP>
__device__ inline void pack_pe_one(const float* __restrict__ p,
                                   const float* __restrict__ e,
                                   _Float16* __restrict__ pe, int idx) {
  int node = idx / D;
  int slot = idx % D;

  const float* pp = p + (size_t)idx * 3;
  float p0 = pp[0], p1 = pp[1], p2 = pp[2];
  float pn = sqrtf(p0 * p0 + p1 * p1 + p2 * p2);
  float rp = pn > 0.f ? 1.f / pn : 0.f;

  const float4* ee = reinterpret_cast<const float4*>(e + (size_t)idx * 8);
  float4 e0 = ee[0];
  float4 e1 = ee[1];
  float en = sqrtf(e0.x * e0.x + e0.y * e0.y + e0.z * e0.z + e0.w * e0.w +
                   e1.x * e1.x + e1.y * e1.y + e1.z * e1.z + e1.w * e1.w);
  float re = en > 0.f ? 1.f / en : 0.f;

  half8 h0, h1;
  h0[0] = (_Float16)(p0 * rp); h0[1] = (_Float16)(p1 * rp);
  h0[2] = (_Float16)(p2 * rp); h0[3] = (_Float16)0.f;
  h0[4] = (_Float16)(e0.x * re); h0[5] = (_Float16)(e0.y * re);
  h0[6] = (_Float16)(e0.z * re); h0[7] = (_Float16)(e0.w * re);
  h1[0] = (_Float16)(e1.x * re); h1[1] = (_Float16)(e1.y * re);
  h1[2] = (_Float16)(e1.z * re); h1[3] = (_Float16)(e1.w * re);
  h1[4] = (_Float16)0.f; h1[5] = (_Float16)0.f;
  h1[6] = (_Float16)0.f; h1[7] = (_Float16)0.f;

  _Float16* dst = pe + (size_t)node * PEP + slot * 16;
  *reinterpret_cast<half8*>(dst)     = h0;
  *reinterpret_cast<half8*>(dst + 8) = h1;

  half8 z = {};
  if (D == 1) {  // pad [16,32)
    _Float16* pz = pe + (size_t)node * PEP + 16;
    *reinterpret_cast<half8*>(pz)     = z;
    *reinterpret_cast<half8*>(pz + 8) = z;
  }
  if (D == 3 && slot == 0) {  // pad [48,64)
    _Float16* pz = pe + (size_t)node * PEP + 48;
    *reinterpret_cast<half8*>(pz)     = z;
    *reinterpret_cast<half8*>(pz + 8) = z;
  }
}

// ---------------------------------------------------------------------------
// Fused prep kernel: grid = [norm blocks | pe blocks | 4 weight blocks]
// ---------------------------------------------------------------------------
struct PrepArgs {
  const float* x; _Float16* xhat; int N; int nb_norm;
  const float* p[4]; const float* e[4]; _Float16* pe[4];
  int slotOff[5]; int nb_pe;
  WPtrs w[4]; _Float16* psi;
};

__global__ __launch_bounds__(256) void k_prep(PrepArgs a) {
  int bid = blockIdx.x, tid = threadIdx.x;

  if (bid < a.nb_norm) {
    // ---- normalize x rows: 4 lanes per row ----
    int row = bid * 64 + (tid >> 2);
    int q   = tid & 3;
    if (row >= a.N) return;
    const float4* xr = reinterpret_cast<const float4*>(a.x + (size_t)row * 32 + q * 8);
    float4 va = xr[0];
    float4 vb = xr[1];
    float ss = va.x * va.x + va.y * va.y + va.z * va.z + va.w * va.w +
               vb.x * vb.x + vb.y * vb.y + vb.z * vb.z + vb.w * vb.w;
    ss += __shfl_xor(ss, 1);
    ss += __shfl_xor(ss, 2);
    float rn = ss > 0.f ? rsqrtf(ss) : 0.f;
    half8 h;
    h[0] = (_Float16)(va.x * rn); h[1] = (_Float16)(va.y * rn);
    h[2] = (_Float16)(va.z * rn); h[3] = (_Float16)(va.w * rn);
    h[4] = (_Float16)(vb.x * rn); h[5] = (_Float16)(vb.y * rn);
    h[6] = (_Float16)(vb.z * rn); h[7] = (_Float16)(vb.w * rn);
    *reinterpret_cast<half8*>(a.xhat + (size_t)row * 32 + q * 8) = h;
    return;
  }

  if (bid < a.nb_norm + a.nb_pe) {
    // ---- pack p/e slots, all groups ----
    int s = (bid - a.nb_norm) * 256 + tid;
    if (s >= a.slotOff[4]) return;
    if      (s < a.slotOff[1]) pack_pe_one<1, 32>(a.p[0], a.e[0], a.pe[0], s);
    else if (s < a.slotOff[2]) pack_pe_one<2, 32>(a.p[1], a.e[1], a.pe[1], s - a.slotOff[1]);
    else if (s < a.slotOff[3]) pack_pe_one<3, 64>(a.p[2], a.e[2], a.pe[2], s - a.slotOff[2]);
    else                       pack_pe_one<4, 64>(a.p[3], a.e[3], a.pe[3], s - a.slotOff[3]);
    return;
  }

  // ---- pack weights: one block per group ----
  int g = bid - a.nb_norm - a.nb_pe;  // 0..3
  int d = g + 1;
  int PEP = (d <= 2) ? 32 : 64;
  int KD  = 32 * (1 + d) + PEP;
  _Float16* pg = a.psi + (size_t)g * (16 * 224);

  for (int i = tid; i < 16 * KD; i += 256) pg[i] = (_Float16)0.f;
  __syncthreads();

  int k     = tid & 15;
  int piece = tid >> 4;
  int np    = 1 + 3 * d;
  if (piece >= np) return;

  const WPtrs& w = a.w[g];
  const float* src;
  _Float16* dst;
  int len;
  float scale;
  if (piece == 0) {
    src = w.wc + k * 32; dst = pg + k * KD; len = 32; scale = 0.25f;
  } else if (piece <= d) {
    int s = piece - 1;
    src = w.wn + (size_t)(k * d + s) * 32; dst = pg + k * KD + 32 * (1 + s);
    len = 32; scale = 0.25f / d;
  } else if (piece <= 2 * d) {
    int s = piece - 1 - d;
    src = w.wp + (size_t)(k * d + s) * 3;
    dst = pg + k * KD + 32 * (1 + d) + 16 * s;
    len = 3; scale = 0.25f / d;
  } else {
    int s = piece - 1 - 2 * d;
    src = w.we + (size_t)(k * d + s) * 8;
    dst = pg + k * KD + 32 * (1 + d) + 16 * s + 4;
    len = 8; scale = 0.25f / d;
  }
  float ss = 0.f;
  for (int j = 0; j < len; ++j) ss += src[j] * src[j];
  float n  = sqrtf(ss);
  float sc = n > 0.f ? scale / n : 0.f;
  for (int j = 0; j < len; ++j) dst[j] = (_Float16)(src[j] * sc);
}

// ---------------------------------------------------------------------------
// Fused main kernel: gathered MFMA GEMM for all 4 groups, NCH chunks per wave
// for memory-level parallelism. Phases: indices -> A-gathers -> MFMA -> store.
// MFMA 16x16x32 f16:  A row = lane&15, B col = lane&15, k-chunk = lane>>4.
// C/D: col = lane&15, row = (lane>>4)*4 + reg  [verified layout].
// ---------------------------------------------------------------------------
struct MainArgs {
  const _Float16* xhat;
  const _Float16* pe[4];
  const _Float16* psi;       // group g at psi + g*16*224, row stride KD(g)
  const int* sel[4];
  const int* nei[4];
  float* out;
  int nd[4];
  int blkOff[5];             // cumulative block offsets per group
};

template <int D, int PEP, int NCH>
__device__ inline void main_one(const MainArgs& a, int g, int blk) {
  constexpr int NMF  = 1 + D;
  constexpr int PEMF = PEP / 32;
  constexpr int NF   = NMF + PEMF;
  constexpr int KD   = 32 * NF;

  const _Float16* xhat = a.xhat;
  const _Float16* pe   = a.pe[g];
  const _Float16* psi  = a.psi + (size_t)g * (16 * 224);
  const int* sel = a.sel[g];
  const int* nei = a.nei[g];
  int nd = a.nd[g];

  int wave    = threadIdx.x >> 6;
  int lane    = threadIdx.x & 63;
  int nchunks = (nd + 15) >> 4;
  int chunk0  = (blk * 4 + wave) * NCH;
  if (chunk0 >= nchunks) return;
  int r = lane & 15;   // A row / B col / C col
  int c = lane >> 4;   // k-chunk

  // B fragments: loaded once, constant for the whole kernel.
  half8 bx[NF];
  {
    const _Float16* pb = psi + (size_t)r * KD + c * 8;
#pragma unroll
    for (int t = 0; t < NF; ++t)
      bx[t] = *reinterpret_cast<const half8*>(pb + 32 * t);
  }

  // ---- phase 1: indices for all NCH chunks (independent loads) ----
  int riA[NCH];
  int sidx[NCH];
  int gidx[NCH][D];
#pragma unroll
  for (int u = 0; u < NCH; ++u) {
    int chunk = chunk0 + u;
    int ri = (chunk < nchunks) ? (chunk * 16 + r) : 0;
    if (ri > nd - 1) ri = nd - 1;
    riA[u]  = ri;
    sidx[u] = sel[ri];
  }
#pragma unroll
  for (int u = 0; u < NCH; ++u)
#pragma unroll
    for (int s = 0; s < D; ++s)
      gidx[u][s] = nei[(size_t)riA[u] * D + s];

  // ---- phase 2: A fragments for all chunks (independent gathers) ----
  half8 af[NCH][NF];
#pragma unroll
  for (int u = 0; u < NCH; ++u) {
    af[u][0] = *reinterpret_cast<const half8*>(xhat + (size_t)sidx[u] * 32 + c * 8);
#pragma unroll
    for (int s = 0; s < D; ++s)
      af[u][1 + s] = *reinterpret_cast<const half8*>(xhat + (size_t)gidx[u][s] * 32 + c * 8);
#pragma unroll
    for (int m = 0; m < PEMF; ++m)
      af[u][NMF + m] = *reinterpret_cast<const half8*>(pe + (size_t)riA[u] * PEP + 32 * m + c * 8);
  }

  // ---- phase 3: MFMAs ----
  floatx4 acc[NCH];
#pragma unroll
  for (int u = 0; u < NCH; ++u) {
    acc[u] = floatx4{0.f, 0.f, 0.f, 0.f};
#pragma unroll
    for (int t = 0; t < NF; ++t)
      acc[u] = __builtin_amdgcn_mfma_f32_16x16x32_f16(af[u][t], bx[t], acc[u], 0, 0, 0);
  }

  // ---- phase 4: writeback ----
#pragma unroll
  for (int u = 0; u < NCH; ++u) {
    int chunk = chunk0 + u;
    if (chunk >= nchunks) break;
    int i0 = chunk << 4;
#pragma unroll
    for (int j = 0; j < 4; ++j) {
      int n  = i0 + c * 4 + j;
      int so = __shfl(sidx[u], c * 4 + j);  // sel[i0 + c*4 + j]
      if (n < nd) {
        float* orow = a.out + (size_t)so * 64 + r;
#pragma unroll
        for (int q = 0; q < 4; ++q)
          orow[q * 16] = (q == D - 1) ? acc[u][j] : 0.f;
      }
    }
  }
}

__global__ __launch_bounds__(256) void k_main(MainArgs a) {
  int bid = blockIdx.x;
  if (bid < a.blkOff[1])      main_one<1, 32, 4>(a, 0, bid);
  else if (bid < a.blkOff[2]) main_one<2, 32, 4>(a, 1, bid - a.blkOff[1]);
  else if (bid < a.blkOff[3]) main_one<3, 64, 3>(a, 2, bid - a.blkOff[2]);
  else                        main_one<4, 64, 2>(a, 3, bid - a.blkOff[3]);
}

// ---------------------------------------------------------------------------
extern "C" void kernel_launch(void* const* d_in, const int* in_sizes, int n_in,
                              void* d_out, int out_size, void* d_ws, size_t ws_size,
                              hipStream_t stream) {
  const float* x = (const float*)d_in[0];
  int N = in_sizes[0] / 32;

  PrepArgs pa;
  MainArgs ma;
  pa.x = x; pa.N = N;
  int nd[4];
  for (int g = 0; g < 4; ++g) {
    int b = 1 + g * 8;
    ma.sel[g]  = (const int*)d_in[b + 0];
    ma.nei[g]  = (const int*)d_in[b + 1];
    pa.p[g]    = (const float*)d_in[b + 2];
    pa.e[g]    = (const float*)d_in[b + 3];
    pa.w[g].wc = (const float*)d_in[b + 4];
    pa.w[g].wn = (const float*)d_in[b + 5];
    pa.w[g].wp = (const float*)d_in[b + 6];
    pa.w[g].we = (const float*)d_in[b + 7];
    nd[g] = in_sizes[b];
    ma.nd[g] = nd[g];
  }
  ma.out = (float*)d_out;

  // workspace layout
  char* ws = (char*)d_ws;
  auto align256 = [](size_t o) { return (o + 255) & ~(size_t)255; };
  _Float16* xhat = (_Float16*)ws;
  size_t off = (size_t)N * 32 * 2;
  for (int g = 0; g < 4; ++g) {
    off = align256(off);
    pa.pe[g] = (_Float16*)(ws + off);
    ma.pe[g] = pa.pe[g];
    off += (size_t)nd[g] * ((g < 2) ? 32 : 64) * 2;
  }
  off = align256(off);
  _Float16* psi = (_Float16*)(ws + off);
  pa.psi = psi;
  ma.psi = psi;
  pa.xhat = xhat;
  ma.xhat = xhat;

  // prep grid: [norm | pe | 4 weight blocks]
  pa.nb_norm = (N + 63) / 64;
  pa.slotOff[0] = 0;
  for (int g = 0; g < 4; ++g) pa.slotOff[g + 1] = pa.slotOff[g] + nd[g] * (g + 1);
  pa.nb_pe = (pa.slotOff[4] + 255) / 256;
  int prep_blocks = pa.nb_norm + pa.nb_pe + 4;

  // main grid: per-group block counts (4 waves/block, NCH chunks/wave)
  const int NCHg[4] = {4, 4, 3, 2};
  ma.blkOff[0] = 0;
  for (int g = 0; g < 4; ++g) {
    int ch = (nd[g] + 15) / 16;
    int perBlk = 4 * NCHg[g];
    ma.blkOff[g + 1] = ma.blkOff[g] + (ch + perBlk - 1) / perBlk;
  }

  k_prep<<<prep_blocks, 256, 0, stream>>>(pa);
  k_main<<<ma.blkOff[4], 256, 0, stream>>>(ma);
}